// Round 6
// baseline (182.827 us; speedup 1.0000x reference)
//
#include <hip/hip_runtime.h>
#include <hip/hip_bf16.h>

typedef __bf16 bf16;
typedef __bf16 bf16x8 __attribute__((ext_vector_type(8)));
typedef float f32x4 __attribute__((ext_vector_type(4)));

static constexpr int Bn = 4, Sn = 2048, Dn = 1024, Hn = 16, HDn = 64;
static constexpr int Mn = Bn * Sn;  // 8192

__device__ __forceinline__ void gload_lds16(const void* g, void* l) {
  __builtin_amdgcn_global_load_lds(
      (const __attribute__((address_space(1))) unsigned int*)g,
      (__attribute__((address_space(3))) unsigned int*)l, 16, 0, 0);
}

// ---------------- prep: x fp32 -> bf16 ----------------
__global__ void cvt_x_kernel(const float* __restrict__ x, bf16* __restrict__ xb, int n8) {
  int i = blockIdx.x * blockDim.x + threadIdx.x;
  if (i >= n8) return;
  const float4* p = reinterpret_cast<const float4*>(x) + (size_t)i * 2;
  float4 a = p[0], b = p[1];
  bf16x8 v;
  v[0] = (bf16)a.x; v[1] = (bf16)a.y; v[2] = (bf16)a.z; v[3] = (bf16)a.w;
  v[4] = (bf16)b.x; v[5] = (bf16)b.y; v[6] = (bf16)b.z; v[7] = (bf16)b.w;
  *(reinterpret_cast<bf16x8*>(xb) + i) = v;
}

// ---------------- prep: W [K][N] fp32 -> Wt [N][K] bf16 ----------------
struct alignas(8) B4 { bf16 e[4]; };

__global__ void transpose_w_kernel(const float* __restrict__ W0, const float* __restrict__ W1,
                                   const float* __restrict__ W2, const float* __restrict__ W3,
                                   bf16* __restrict__ WtQKV, bf16* __restrict__ Wot) {
  __shared__ bf16 tile[64][65];
  const int which = blockIdx.z;
  const float* W = (which == 0) ? W0 : (which == 1) ? W1 : (which == 2) ? W2 : W3;
  bf16* out = (which < 3) ? (WtQKV + (size_t)which * 1024 * 1024) : Wot;
  const int k0 = blockIdx.y * 64, n0 = blockIdx.x * 64;
  const int t = threadIdx.x;
  const int tr = t >> 4, tc = (t & 15) * 4;
#pragma unroll
  for (int rr = 0; rr < 4; ++rr) {
    const int row = rr * 16 + tr;
    float4 v = *reinterpret_cast<const float4*>(&W[(size_t)(k0 + row) * 1024 + n0 + tc]);
    tile[row][tc + 0] = (bf16)v.x; tile[row][tc + 1] = (bf16)v.y;
    tile[row][tc + 2] = (bf16)v.z; tile[row][tc + 3] = (bf16)v.w;
  }
  __syncthreads();
#pragma unroll
  for (int rr = 0; rr < 4; ++rr) {
    const int row = rr * 16 + tr;  // n index
    B4 o;
#pragma unroll
    for (int j = 0; j < 4; ++j) o.e[j] = tile[tc + j][row];
    *reinterpret_cast<B4*>(&out[(size_t)(n0 + row) * 1024 + k0 + tc]) = o;
  }
}

// ---------------- GEMM: C[M][N] = A[M][1024] @ Bt[N][1024]^T ----------------
// T2 XOR-swizzled LDS, double-buffered with prefetch.
// MODE 0: Q output pre-scaled by 1/sqrt(64)*log2(e) (folded softmax scale).
template <int MODE>
__global__ __launch_bounds__(256, 2)
void gemm_kernel(const bf16* __restrict__ A, const bf16* __restrict__ Bt,
                 float* __restrict__ Co, const float* __restrict__ bias,
                 bf16* __restrict__ Qo, bf16* __restrict__ Ko, bf16* __restrict__ Vto) {
  __shared__ bf16 Al[2][128 * 64];
  __shared__ bf16 Bl[2][128 * 64];
  const int tid = threadIdx.x;
  const int lane = tid & 63;
  const int wv = tid >> 6;
  const int wm = wv >> 1, wn = wv & 1;
  const int lr = lane & 15, lg = lane >> 4;
  const int m0 = blockIdx.y * 128, n0 = blockIdx.x * 128;

  int soff[4];
  const bf16* srcA[4];
  const bf16* srcB[4];
#pragma unroll
  for (int it = 0; it < 4; ++it) {
    const int elem = it * 2048 + tid * 8;
    const int row = elem >> 6;
    const int g = (elem >> 3) & 7;
    const int gs = g ^ (row & 7);
    soff[it] = elem;
    srcA[it] = A + (size_t)(m0 + row) * 1024 + gs * 8;
    srcB[it] = Bt + (size_t)(n0 + row) * 1024 + gs * 8;
  }

  f32x4 acc[4][4] = {};

#pragma unroll
  for (int it = 0; it < 4; ++it) {
    gload_lds16(srcA[it], (bf16*)&Al[0][0] + soff[it]);
    gload_lds16(srcB[it], (bf16*)&Bl[0][0] + soff[it]);
  }
  __syncthreads();

  for (int ks = 0; ks < 16; ++ks) {
    const int cur = ks & 1;
    if (ks + 1 < 16) {
      const int kn = (ks + 1) * 64;
#pragma unroll
      for (int it = 0; it < 4; ++it) {
        gload_lds16(srcA[it] + kn, (bf16*)&Al[cur ^ 1][0] + soff[it]);
        gload_lds16(srcB[it] + kn, (bf16*)&Bl[cur ^ 1][0] + soff[it]);
      }
    }
    const bf16* AlF = Al[cur];
    const bf16* BlF = Bl[cur];
#pragma unroll
    for (int kk = 0; kk < 2; ++kk) {
      bf16x8 af[4], bfr[4];
#pragma unroll
      for (int i = 0; i < 4; ++i) {
        const int row = wm * 64 + i * 16 + lr;
        af[i] = *reinterpret_cast<const bf16x8*>(AlF + row * 64 + (((kk * 4 + lg) ^ (row & 7)) << 3));
      }
#pragma unroll
      for (int i = 0; i < 4; ++i) {
        const int row = wn * 64 + i * 16 + lr;
        bfr[i] = *reinterpret_cast<const bf16x8*>(BlF + row * 64 + (((kk * 4 + lg) ^ (row & 7)) << 3));
      }
#pragma unroll
      for (int mi = 0; mi < 4; ++mi)
#pragma unroll
        for (int ni = 0; ni < 4; ++ni)
          acc[mi][ni] = __builtin_amdgcn_mfma_f32_16x16x32_bf16(af[mi], bfr[ni], acc[mi][ni], 0, 0, 0);
    }
    __syncthreads();
  }

  const int mrow = lg * 4;
  if (MODE == 0) {
    const int w = n0 >> 10;
    const int nl0 = n0 & 1023;
    if (w == 2) {
      const int b = m0 >> 11;
      const int s0 = (m0 & 2047) + wm * 64 + mrow;
#pragma unroll
      for (int ni = 0; ni < 4; ++ni) {
        const int nl = nl0 + wn * 64 + ni * 16 + lr;
        const int h = nl >> 6, hd = nl & 63;
        bf16* vbase = Vto + ((size_t)(b * 16 + h) * 64 + hd) * 2048;
#pragma unroll
        for (int mi = 0; mi < 4; ++mi) {
          B4 o;
#pragma unroll
          for (int i = 0; i < 4; ++i) o.e[i] = (bf16)acc[mi][ni][i];
          *reinterpret_cast<B4*>(&vbase[s0 + mi * 16]) = o;
        }
      }
    } else {
      // Q gets the softmax scale folded in (1/sqrt(64) * log2(e))
      const float fs = (w == 0) ? 0.18033688011112042f : 1.0f;
#pragma unroll
      for (int ni = 0; ni < 4; ++ni) {
        const int nl = nl0 + wn * 64 + ni * 16 + lr;
        const int h = nl >> 6, hd = nl & 63;
        bf16* dst = (w == 0) ? Qo : Ko;
#pragma unroll
        for (int mi = 0; mi < 4; ++mi) {
#pragma unroll
          for (int i = 0; i < 4; ++i) {
            const int m_g = m0 + wm * 64 + mi * 16 + mrow + i;
            const int b = m_g >> 11, s = m_g & 2047;
            dst[((size_t)(b * 16 + h) * 2048 + s) * 64 + hd] = (bf16)(acc[mi][ni][i] * fs);
          }
        }
      }
    }
  } else {
#pragma unroll
    for (int ni = 0; ni < 4; ++ni) {
      const int n_g = n0 + wn * 64 + ni * 16 + lr;
      const float bv = bias[n_g];
#pragma unroll
      for (int mi = 0; mi < 4; ++mi) {
#pragma unroll
        for (int i = 0; i < 4; ++i) {
          const int m_g = m0 + wm * 64 + mi * 16 + mrow + i;
          Co[(size_t)m_g * 1024 + n_g] = acc[mi][ni][i] + bv;
        }
      }
    }
  }
}

// ---------------- causal flash attention -----------------------------------
// Swapped QK^T (lane-local q-row), static-max softmax, and P redistributed to
// the PV fragment layout IN REGISTERS via shfl (no P LDS, no store->load
// chain; A/B q-tile chains fully independent). PV computed swapped too:
// acc = mfma(A=V^T, B=P) so acc rows are lane-local q=lr -> cheap epilogue.
// Redistribution math (key-pair kp: src kp={ni,lg_s,tt}, dst kp={kk,lg,w}):
//   lg_s = 2*(lg&1) + (w>>1), ni = 2*kk + (lg>>1), tt = w&1.
__device__ __forceinline__ void attn_tile(const bf16* __restrict__ KlF,
                                          const bf16* __restrict__ VlF,
                                          const bf16x8 (&aq)[2], f32x4 (&acc)[4],
                                          float& lst, int kv0, int qrow, bool domask,
                                          int lr, int lg, int src0, int src1) {
  // S^T = mfma(K, Q): sc[ni][r] = S[q = qrow][key = kv0 + ni*16 + lg*4 + r]
  f32x4 sc[4] = {};
#pragma unroll
  for (int kk = 0; kk < 2; ++kk) {
    bf16x8 ak[4];
#pragma unroll
    for (int ni = 0; ni < 4; ++ni) {
      const int row = ni * 16 + lr;
      ak[ni] = *reinterpret_cast<const bf16x8*>(KlF + row * 64 + (((kk * 4 + lg) ^ (row & 7)) << 3));
    }
    __builtin_amdgcn_s_setprio(1);
#pragma unroll
    for (int ni = 0; ni < 4; ++ni)
      sc[ni] = __builtin_amdgcn_mfma_f32_16x16x32_bf16(ak[ni], aq[kk], sc[ni], 0, 0, 0);
    __builtin_amdgcn_s_setprio(0);
  }
  // static-max softmax: p = 2^score (score already includes 1/sqrt(hd)*log2e)
  float p[4][4];
  float rs = 0.f;
#pragma unroll
  for (int ni = 0; ni < 4; ++ni)
#pragma unroll
    for (int r = 0; r < 4; ++r) {
      float pv = __builtin_amdgcn_exp2f(sc[ni][r]);
      if (domask && (kv0 + ni * 16 + lg * 4 + r > qrow)) pv = 0.f;
      p[ni][r] = pv;
      rs += pv;
    }
  rs += __shfl_xor(rs, 16);
  rs += __shfl_xor(rs, 32);
  lst += rs;
  // pack to bf16-pair words: pk[ni][tt] = keys (ni*16+lg*4+2tt, +1) of q=lr
  unsigned int pk[4][2];
#pragma unroll
  for (int ni = 0; ni < 4; ++ni)
#pragma unroll
    for (int tt = 0; tt < 2; ++tt) {
      union { bf16 bb[2]; unsigned int u; } c;
      c.bb[0] = (bf16)p[ni][2 * tt];
      c.bb[1] = (bf16)p[ni][2 * tt + 1];
      pk[ni][tt] = c.u;
    }
  const bool sel = (lg & 2) != 0;
  // PV swapped: acc[ni] = mfma(A = V^T rows (hd-block ni), B = P frag)
#pragma unroll
  for (int kk = 0; kk < 2; ++kk) {
    union { unsigned int u[4]; bf16x8 v; } ap;
#pragma unroll
    for (int w = 0; w < 4; ++w) {
      const int srcl = (w < 2) ? src0 : src1;
      const unsigned int lo = (unsigned int)__shfl((int)pk[2 * kk][w & 1], srcl);
      const unsigned int hi = (unsigned int)__shfl((int)pk[2 * kk + 1][w & 1], srcl);
      ap.u[w] = sel ? hi : lo;
    }
    bf16x8 bv[4];
#pragma unroll
    for (int ni = 0; ni < 4; ++ni) {
      const int row = ni * 16 + lr;
      bv[ni] = *reinterpret_cast<const bf16x8*>(VlF + row * 64 + (((kk * 4 + lg) ^ (row & 7)) << 3));
    }
    __builtin_amdgcn_s_setprio(1);
#pragma unroll
    for (int ni = 0; ni < 4; ++ni)
      acc[ni] = __builtin_amdgcn_mfma_f32_16x16x32_bf16(bv[ni], ap.v, acc[ni], 0, 0, 0);
    __builtin_amdgcn_s_setprio(0);
  }
}

__global__ __launch_bounds__(256, 4)
void attn_kernel(const bf16* __restrict__ Q, const bf16* __restrict__ K,
                 const bf16* __restrict__ Vt, bf16* __restrict__ ctx) {
  __shared__ bf16 Kl[2][4096];
  __shared__ bf16 Vl[2][4096];
  const int tid = threadIdx.x, lane = tid & 63, wv = tid >> 6;
  const int lr = lane & 15, lg = lane >> 4, lk = lg * 8;
  const int bh = blockIdx.y;
  const int pi = blockIdx.x;
  const bf16* Qh = Q + (size_t)bh * Sn * 64;
  const bf16* Kh = K + (size_t)bh * Sn * 64;
  const bf16* Vh = Vt + (size_t)bh * 64 * (size_t)Sn;
  const int b = bh >> 4, h = bh & 15;
  // shfl source lanes for the P redistribution (within 4-lane column group)
  const int src0 = lr + 32 * (lg & 1);
  const int src1 = src0 + 16;

  const int e0 = tid * 8, e1 = 2048 + tid * 8;
  const int r0 = e0 >> 6, r1 = e1 >> 6;
  const int gs0 = ((e0 >> 3) & 7) ^ (r0 & 7), gs1 = ((e1 >> 3) & 7) ^ (r1 & 7);
  const bf16* srcK0 = Kh + r0 * 64 + gs0 * 8;
  const bf16* srcK1 = Kh + r1 * 64 + gs1 * 8;
  const bf16* srcV0 = Vh + (size_t)r0 * Sn + gs0 * 8;
  const bf16* srcV1 = Vh + (size_t)r1 * Sn + gs1 * 8;

  const int tA = 31 - pi, tB = pi;  // tA > tB always (pi in 0..15)
  const int qwA = tA * 64 + wv * 16, qwB = tB * 64 + wv * 16;
  const int qrowA = qwA + lr, qrowB = qwB + lr;

  bf16x8 aqA[2], aqB[2];
#pragma unroll
  for (int kk = 0; kk < 2; ++kk) {
    aqA[kk] = *reinterpret_cast<const bf16x8*>(&Qh[(size_t)(qwA + lr) * 64 + kk * 32 + lk]);
    aqB[kk] = *reinterpret_cast<const bf16x8*>(&Qh[(size_t)(qwB + lr) * 64 + kk * 32 + lk]);
  }

  f32x4 accA[4] = {}, accB[4] = {};
  float lstA = 0.f, lstB = 0.f;

  // prologue: stage kv-tile 0 into buf 0
  gload_lds16(srcK0, &Kl[0][e0]);
  gload_lds16(srcK1, &Kl[0][e1]);
  gload_lds16(srcV0, &Vl[0][e0]);
  gload_lds16(srcV1, &Vl[0][e1]);
  __syncthreads();

  for (int t = 0; t <= tA; ++t) {
    const int cur = t & 1;
    if (t < tA) {  // prefetch next kv tile into other buffer
      const int kvn = (t + 1) * 64;
      gload_lds16(srcK0 + kvn * 64, &Kl[cur ^ 1][e0]);
      gload_lds16(srcK1 + kvn * 64, &Kl[cur ^ 1][e1]);
      gload_lds16(srcV0 + kvn, &Vl[cur ^ 1][e0]);
      gload_lds16(srcV1 + kvn, &Vl[cur ^ 1][e1]);
    }
    const bf16* KlF = Kl[cur];
    const bf16* VlF = Vl[cur];
    attn_tile(KlF, VlF, aqA, accA, lstA, t * 64, qrowA, t == tA, lr, lg, src0, src1);
    if (t <= tB)
      attn_tile(KlF, VlF, aqB, accB, lstB, t * 64, qrowB, t == tB, lr, lg, src0, src1);
    __syncthreads();  // drains prefetch vmcnt + releases buffers
  }

  // epilogue: acc[ni][r] holds q = qw + lr (lane-local), hd = ni*16 + lg*4 + r
  {
    const float inv = 1.f / lstA;
    bf16* cbase = ctx + (((size_t)b * Sn + qwA + lr) * 16 + h) * 64;
#pragma unroll
    for (int ni = 0; ni < 4; ++ni) {
      B4 o;
#pragma unroll
      for (int r = 0; r < 4; ++r) o.e[r] = (bf16)(accA[ni][r] * inv);
      *reinterpret_cast<B4*>(cbase + ni * 16 + lg * 4) = o;
    }
  }
  {
    const float inv = 1.f / lstB;
    bf16* cbase = ctx + (((size_t)b * Sn + qwB + lr) * 16 + h) * 64;
#pragma unroll
    for (int ni = 0; ni < 4; ++ni) {
      B4 o;
#pragma unroll
      for (int r = 0; r < 4; ++r) o.e[r] = (bf16)(accB[ni][r] * inv);
      *reinterpret_cast<B4*>(cbase + ni * 16 + lg * 4) = o;
    }
  }
}

// ---------------- launch ----------------
extern "C" void kernel_launch(void* const* d_in, const int* in_sizes, int n_in,
                              void* d_out, int out_size, void* d_ws, size_t ws_size,
                              hipStream_t stream) {
  const float* x = (const float*)d_in[0];
  const float* Wq = (const float*)d_in[1];
  const float* Wk = (const float*)d_in[2];
  const float* Wv = (const float*)d_in[3];
  const float* Wo = (const float*)d_in[4];
  const float* bo = (const float*)d_in[5];

  char* ws = (char*)d_ws;
  bf16* xb    = (bf16*)(ws);                       // 16 MiB (reused as ctx later)
  bf16* WtQKV = (bf16*)(ws + 0x1000000);           // 6 MiB
  bf16* Wot   = (bf16*)(ws + 0x1600000);           // 2 MiB
  bf16* Qb    = (bf16*)(ws + 0x1800000);           // 16 MiB
  bf16* Kb    = (bf16*)(ws + 0x2800000);           // 16 MiB
  bf16* Vtb   = (bf16*)(ws + 0x3800000);           // 16 MiB  (end: 72 MiB)
  bf16* ctx   = xb;                                // alias: xb dead after QKV GEMM

  cvt_x_kernel<<<dim3(Mn * Dn / 8 / 256), dim3(256), 0, stream>>>(x, xb, Mn * Dn / 8);
  transpose_w_kernel<<<dim3(16, 16, 4), dim3(256), 0, stream>>>(Wq, Wk, Wv, Wo, WtQKV, Wot);
  gemm_kernel<0><<<dim3(24, 64), dim3(256), 0, stream>>>(xb, WtQKV, nullptr, nullptr, Qb, Kb, Vtb);
  attn_kernel<<<dim3(16, 64), dim3(256), 0, stream>>>(Qb, Kb, Vtb, ctx);
  gemm_kernel<1><<<dim3(8, 64), dim3(256), 0, stream>>>(ctx, Wot, (float*)d_out, bo,
                                                        nullptr, nullptr, nullptr);
}

// Round 9
// 174.255 us; speedup vs baseline: 1.0492x; 1.0492x over previous
//
#include <hip/hip_runtime.h>
#include <hip/hip_bf16.h>

typedef __bf16 bf16;
typedef __bf16 bf16x4 __attribute__((ext_vector_type(4)));
typedef __bf16 bf16x8 __attribute__((ext_vector_type(8)));
typedef float f32x4 __attribute__((ext_vector_type(4)));

static constexpr int Bn = 4, Sn = 2048, Dn = 1024, Hn = 16, HDn = 64;
static constexpr int Mn = Bn * Sn;  // 8192

__device__ __forceinline__ void gload_lds16(const void* g, void* l) {
  __builtin_amdgcn_global_load_lds(
      (const __attribute__((address_space(1))) unsigned int*)g,
      (__attribute__((address_space(3))) unsigned int*)l, 16, 0, 0);
}

// ---------------- prep: x fp32 -> bf16 ----------------
__global__ void cvt_x_kernel(const float* __restrict__ x, bf16* __restrict__ xb, int n8) {
  int i = blockIdx.x * blockDim.x + threadIdx.x;
  if (i >= n8) return;
  const float4* p = reinterpret_cast<const float4*>(x) + (size_t)i * 2;
  float4 a = p[0], b = p[1];
  bf16x8 v;
  v[0] = (bf16)a.x; v[1] = (bf16)a.y; v[2] = (bf16)a.z; v[3] = (bf16)a.w;
  v[4] = (bf16)b.x; v[5] = (bf16)b.y; v[6] = (bf16)b.z; v[7] = (bf16)b.w;
  *(reinterpret_cast<bf16x8*>(xb) + i) = v;
}

// ---------------- prep: W [K][N] fp32 -> Wt [N][K] bf16 ----------------
struct alignas(8) B4 { bf16 e[4]; };

__global__ void transpose_w_kernel(const float* __restrict__ W0, const float* __restrict__ W1,
                                   const float* __restrict__ W2, const float* __restrict__ W3,
                                   bf16* __restrict__ WtQKV, bf16* __restrict__ Wot) {
  __shared__ bf16 tile[64][65];
  const int which = blockIdx.z;
  const float* W = (which == 0) ? W0 : (which == 1) ? W1 : (which == 2) ? W2 : W3;
  bf16* out = (which < 3) ? (WtQKV + (size_t)which * 1024 * 1024) : Wot;
  const int k0 = blockIdx.y * 64, n0 = blockIdx.x * 64;
  const int t = threadIdx.x;
  const int tr = t >> 4, tc = (t & 15) * 4;
#pragma unroll
  for (int rr = 0; rr < 4; ++rr) {
    const int row = rr * 16 + tr;
    float4 v = *reinterpret_cast<const float4*>(&W[(size_t)(k0 + row) * 1024 + n0 + tc]);
    tile[row][tc + 0] = (bf16)v.x; tile[row][tc + 1] = (bf16)v.y;
    tile[row][tc + 2] = (bf16)v.z; tile[row][tc + 3] = (bf16)v.w;
  }
  __syncthreads();
#pragma unroll
  for (int rr = 0; rr < 4; ++rr) {
    const int row = rr * 16 + tr;  // n index
    B4 o;
#pragma unroll
    for (int j = 0; j < 4; ++j) o.e[j] = tile[tc + j][row];
    *reinterpret_cast<B4*>(&out[(size_t)(n0 + row) * 1024 + k0 + tc]) = o;
  }
}

// ---------------- GEMM: C[M][N] = A[M][1024] @ Bt[N][1024]^T ----------------
// T2 XOR-swizzled LDS, double-buffered with prefetch.
// MODE 0: Q output pre-scaled by 1/sqrt(64)*log2(e) (folded softmax scale).
template <int MODE>
__global__ __launch_bounds__(256, 2)
void gemm_kernel(const bf16* __restrict__ A, const bf16* __restrict__ Bt,
                 float* __restrict__ Co, const float* __restrict__ bias,
                 bf16* __restrict__ Qo, bf16* __restrict__ Ko, bf16* __restrict__ Vto) {
  __shared__ bf16 Al[2][128 * 64];
  __shared__ bf16 Bl[2][128 * 64];
  const int tid = threadIdx.x;
  const int lane = tid & 63;
  const int wv = tid >> 6;
  const int wm = wv >> 1, wn = wv & 1;
  const int lr = lane & 15, lg = lane >> 4;
  const int m0 = blockIdx.y * 128, n0 = blockIdx.x * 128;

  int soff[4];
  const bf16* srcA[4];
  const bf16* srcB[4];
#pragma unroll
  for (int it = 0; it < 4; ++it) {
    const int elem = it * 2048 + tid * 8;
    const int row = elem >> 6;
    const int g = (elem >> 3) & 7;
    const int gs = g ^ (row & 7);
    soff[it] = elem;
    srcA[it] = A + (size_t)(m0 + row) * 1024 + gs * 8;
    srcB[it] = Bt + (size_t)(n0 + row) * 1024 + gs * 8;
  }

  f32x4 acc[4][4] = {};

#pragma unroll
  for (int it = 0; it < 4; ++it) {
    gload_lds16(srcA[it], (bf16*)&Al[0][0] + soff[it]);
    gload_lds16(srcB[it], (bf16*)&Bl[0][0] + soff[it]);
  }
  __syncthreads();

  for (int ks = 0; ks < 16; ++ks) {
    const int cur = ks & 1;
    if (ks + 1 < 16) {
      const int kn = (ks + 1) * 64;
#pragma unroll
      for (int it = 0; it < 4; ++it) {
        gload_lds16(srcA[it] + kn, (bf16*)&Al[cur ^ 1][0] + soff[it]);
        gload_lds16(srcB[it] + kn, (bf16*)&Bl[cur ^ 1][0] + soff[it]);
      }
    }
    const bf16* AlF = Al[cur];
    const bf16* BlF = Bl[cur];
#pragma unroll
    for (int kk = 0; kk < 2; ++kk) {
      bf16x8 af[4], bfr[4];
#pragma unroll
      for (int i = 0; i < 4; ++i) {
        const int row = wm * 64 + i * 16 + lr;
        af[i] = *reinterpret_cast<const bf16x8*>(AlF + row * 64 + (((kk * 4 + lg) ^ (row & 7)) << 3));
      }
#pragma unroll
      for (int i = 0; i < 4; ++i) {
        const int row = wn * 64 + i * 16 + lr;
        bfr[i] = *reinterpret_cast<const bf16x8*>(BlF + row * 64 + (((kk * 4 + lg) ^ (row & 7)) << 3));
      }
#pragma unroll
      for (int mi = 0; mi < 4; ++mi)
#pragma unroll
        for (int ni = 0; ni < 4; ++ni)
          acc[mi][ni] = __builtin_amdgcn_mfma_f32_16x16x32_bf16(af[mi], bfr[ni], acc[mi][ni], 0, 0, 0);
    }
    __syncthreads();
  }

  const int mrow = lg * 4;
  if (MODE == 0) {
    const int w = n0 >> 10;
    const int nl0 = n0 & 1023;
    if (w == 2) {
      const int b = m0 >> 11;
      const int s0 = (m0 & 2047) + wm * 64 + mrow;
#pragma unroll
      for (int ni = 0; ni < 4; ++ni) {
        const int nl = nl0 + wn * 64 + ni * 16 + lr;
        const int h = nl >> 6, hd = nl & 63;
        bf16* vbase = Vto + ((size_t)(b * 16 + h) * 64 + hd) * 2048;
#pragma unroll
        for (int mi = 0; mi < 4; ++mi) {
          B4 o;
#pragma unroll
          for (int i = 0; i < 4; ++i) o.e[i] = (bf16)acc[mi][ni][i];
          *reinterpret_cast<B4*>(&vbase[s0 + mi * 16]) = o;
        }
      }
    } else {
      // Q gets the softmax scale folded in (1/sqrt(64) * log2(e))
      const float fs = (w == 0) ? 0.18033688011112042f : 1.0f;
#pragma unroll
      for (int ni = 0; ni < 4; ++ni) {
        const int nl = nl0 + wn * 64 + ni * 16 + lr;
        const int h = nl >> 6, hd = nl & 63;
        bf16* dst = (w == 0) ? Qo : Ko;
#pragma unroll
        for (int mi = 0; mi < 4; ++mi) {
#pragma unroll
          for (int i = 0; i < 4; ++i) {
            const int m_g = m0 + wm * 64 + mi * 16 + mrow + i;
            const int b = m_g >> 11, s = m_g & 2047;
            dst[((size_t)(b * 16 + h) * 2048 + s) * 64 + hd] = (bf16)(acc[mi][ni][i] * fs);
          }
        }
      }
    }
  } else {
#pragma unroll
    for (int ni = 0; ni < 4; ++ni) {
      const int n_g = n0 + wn * 64 + ni * 16 + lr;
      const float bv = bias[n_g];
#pragma unroll
      for (int mi = 0; mi < 4; ++mi) {
#pragma unroll
        for (int i = 0; i < 4; ++i) {
          const int m_g = m0 + wm * 64 + mi * 16 + mrow + i;
          Co[(size_t)m_g * 1024 + n_g] = acc[mi][ni][i] + bv;
        }
      }
    }
  }
}

// ---------------- causal flash attention (16x16 MFMA, pi-retimed PV) -------
// Verified round-6 structure (swapped QK^T, lane-local q-row softmax, swapped
// PV -> O^T), with the P redistribution ELIMINATED via the mfma k-bijection
// freedom: for PV step kk, k-slot (lg, j) -> key kk*32 + 16*(j>>2) + 4*lg +
// (j&3), applied to BOTH V's A-fragment (two b64 reads) and P's B-fragment.
// Under this map, B word w == the lane's own packed register pk[2kk+(w>>1)][w&1].
// No cross-lane ops, no P LDS. Shared-bijection validity is HW-verified at
// 16x16x32 by the passing GEMMs (A and B loaded with the same (lg,j)->k map).
__device__ __forceinline__ unsigned int pack2(float lo, float hi) {
  union { bf16 bb[2]; unsigned int u; } c;
  c.bb[0] = (bf16)lo; c.bb[1] = (bf16)hi;
  return c.u;
}

__device__ __forceinline__ void attn_tile(const bf16* __restrict__ KlF,
                                          const bf16* __restrict__ VlF,
                                          const bf16x8 (&aq)[2], f32x4 (&acc)[4],
                                          float& lst, int kv0, int qrow, bool domask,
                                          int lr, int lg) {
  // S^T = mfma(K, Q): sc[ni][r] = S[q = qrow][key = kv0 + ni*16 + lg*4 + r]
  f32x4 sc[4] = {};
#pragma unroll
  for (int kk = 0; kk < 2; ++kk) {
    bf16x8 ak[4];
#pragma unroll
    for (int ni = 0; ni < 4; ++ni) {
      const int row = ni * 16 + lr;
      ak[ni] = *reinterpret_cast<const bf16x8*>(KlF + row * 64 + (((kk * 4 + lg) ^ (row & 7)) << 3));
    }
    __builtin_amdgcn_s_setprio(1);
#pragma unroll
    for (int ni = 0; ni < 4; ++ni)
      sc[ni] = __builtin_amdgcn_mfma_f32_16x16x32_bf16(ak[ni], aq[kk], sc[ni], 0, 0, 0);
    __builtin_amdgcn_s_setprio(0);
  }
  // static-max softmax: p = 2^score (score already includes 1/sqrt(hd)*log2e)
  float p[4][4];
  float rs = 0.f;
#pragma unroll
  for (int ni = 0; ni < 4; ++ni)
#pragma unroll
    for (int r = 0; r < 4; ++r) {
      float pv = __builtin_amdgcn_exp2f(sc[ni][r]);
      if (domask && (kv0 + ni * 16 + lg * 4 + r > qrow)) pv = 0.f;
      p[ni][r] = pv;
      rs += pv;
    }
  rs += __shfl_xor(rs, 16);
  rs += __shfl_xor(rs, 32);
  lst += rs;
  // pack: pk[ni][tt] = bf16 pair (keys ni*16 + lg*4 + 2tt, +1) of q = lr
  unsigned int pk[4][2];
#pragma unroll
  for (int ni = 0; ni < 4; ++ni)
#pragma unroll
    for (int tt = 0; tt < 2; ++tt)
      pk[ni][tt] = pack2(p[ni][2 * tt], p[ni][2 * tt + 1]);
  // PV swapped with pi-retimed k order: acc[ni] = mfma(A = V^T rows, B = own P)
#pragma unroll
  for (int kk = 0; kk < 2; ++kk) {
    union { unsigned int u[4]; bf16x8 v; } ap;
#pragma unroll
    for (int w = 0; w < 4; ++w) ap.u[w] = pk[2 * kk + (w >> 1)][w & 1];
    const int g1 = 4 * kk + (lg >> 1), g2 = g1 + 2, off = 4 * (lg & 1);
#pragma unroll
    for (int ni = 0; ni < 4; ++ni) {
      const int row = ni * 16 + lr;
      union { bf16x4 q[2]; bf16x8 v; } av;
      av.q[0] = *reinterpret_cast<const bf16x4*>(VlF + row * 64 + ((g1 ^ (row & 7)) << 3) + off);
      av.q[1] = *reinterpret_cast<const bf16x4*>(VlF + row * 64 + ((g2 ^ (row & 7)) << 3) + off);
      __builtin_amdgcn_s_setprio(1);
      acc[ni] = __builtin_amdgcn_mfma_f32_16x16x32_bf16(av.v, ap.v, acc[ni], 0, 0, 0);
      __builtin_amdgcn_s_setprio(0);
    }
  }
}

__global__ __launch_bounds__(256, 4)
void attn_kernel(const bf16* __restrict__ Q, const bf16* __restrict__ K,
                 const bf16* __restrict__ Vt, bf16* __restrict__ ctx) {
  __shared__ bf16 Kl[2][4096];
  __shared__ bf16 Vl[2][4096];
  const int tid = threadIdx.x, lane = tid & 63, wv = tid >> 6;
  const int lr = lane & 15, lg = lane >> 4, lk = lg * 8;
  const int bh = blockIdx.y;
  const int pi = blockIdx.x;
  const bf16* Qh = Q + (size_t)bh * Sn * 64;
  const bf16* Kh = K + (size_t)bh * Sn * 64;
  const bf16* Vh = Vt + (size_t)bh * 64 * (size_t)Sn;
  const int b = bh >> 4, h = bh & 15;

  const int e0 = tid * 8, e1 = 2048 + tid * 8;
  const int r0 = e0 >> 6, r1 = e1 >> 6;
  const int gs0 = ((e0 >> 3) & 7) ^ (r0 & 7), gs1 = ((e1 >> 3) & 7) ^ (r1 & 7);
  const bf16* srcK0 = Kh + r0 * 64 + gs0 * 8;
  const bf16* srcK1 = Kh + r1 * 64 + gs1 * 8;
  const bf16* srcV0 = Vh + (size_t)r0 * Sn + gs0 * 8;
  const bf16* srcV1 = Vh + (size_t)r1 * Sn + gs1 * 8;

  const int tA = 31 - pi, tB = pi;  // tA > tB always (pi in 0..15)
  const int qwA = tA * 64 + wv * 16, qwB = tB * 64 + wv * 16;
  const int qrowA = qwA + lr, qrowB = qwB + lr;

  bf16x8 aqA[2], aqB[2];
#pragma unroll
  for (int kk = 0; kk < 2; ++kk) {
    aqA[kk] = *reinterpret_cast<const bf16x8*>(&Qh[(size_t)(qwA + lr) * 64 + kk * 32 + lk]);
    aqB[kk] = *reinterpret_cast<const bf16x8*>(&Qh[(size_t)(qwB + lr) * 64 + kk * 32 + lk]);
  }

  f32x4 accA[4] = {}, accB[4] = {};
  float lstA = 0.f, lstB = 0.f;

  // prologue: stage kv-tile 0 into buf 0
  gload_lds16(srcK0, &Kl[0][e0]);
  gload_lds16(srcK1, &Kl[0][e1]);
  gload_lds16(srcV0, &Vl[0][e0]);
  gload_lds16(srcV1, &Vl[0][e1]);
  __syncthreads();

  for (int t = 0; t <= tA; ++t) {
    const int cur = t & 1;
    if (t < tA) {  // prefetch next kv tile into other buffer
      const int kvn = (t + 1) * 64;
      gload_lds16(srcK0 + kvn * 64, &Kl[cur ^ 1][e0]);
      gload_lds16(srcK1 + kvn * 64, &Kl[cur ^ 1][e1]);
      gload_lds16(srcV0 + kvn, &Vl[cur ^ 1][e0]);
      gload_lds16(srcV1 + kvn, &Vl[cur ^ 1][e1]);
    }
    const bf16* KlF = Kl[cur];
    const bf16* VlF = Vl[cur];
    attn_tile(KlF, VlF, aqA, accA, lstA, t * 64, qrowA, t == tA, lr, lg);
    if (t <= tB)
      attn_tile(KlF, VlF, aqB, accB, lstB, t * 64, qrowB, t == tB, lr, lg);
    __syncthreads();  // drains prefetch vmcnt + releases buffers
  }

  // epilogue: O^T -> lane holds O[q = qw+lr][hd = ni*16 + lg*4 + r]
  {
    const float inv = 1.f / lstA;
    bf16* cbase = ctx + (((size_t)b * Sn + qwA + lr) * 16 + h) * 64;
#pragma unroll
    for (int ni = 0; ni < 4; ++ni) {
      B4 o;
#pragma unroll
      for (int r = 0; r < 4; ++r) o.e[r] = (bf16)(accA[ni][r] * inv);
      *reinterpret_cast<B4*>(cbase + ni * 16 + lg * 4) = o;
    }
  }
  {
    const float inv = 1.f / lstB;
    bf16* cbase = ctx + (((size_t)b * Sn + qwB + lr) * 16 + h) * 64;
#pragma unroll
    for (int ni = 0; ni < 4; ++ni) {
      B4 o;
#pragma unroll
      for (int r = 0; r < 4; ++r) o.e[r] = (bf16)(accB[ni][r] * inv);
      *reinterpret_cast<B4*>(cbase + ni * 16 + lg * 4) = o;
    }
  }
}

// ---------------- launch ----------------
extern "C" void kernel_launch(void* const* d_in, const int* in_sizes, int n_in,
                              void* d_out, int out_size, void* d_ws, size_t ws_size,
                              hipStream_t stream) {
  const float* x = (const float*)d_in[0];
  const float* Wq = (const float*)d_in[1];
  const float* Wk = (const float*)d_in[2];
  const float* Wv = (const float*)d_in[3];
  const float* Wo = (const float*)d_in[4];
  const float* bo = (const float*)d_in[5];

  char* ws = (char*)d_ws;
  bf16* xb    = (bf16*)(ws);                       // 16 MiB (reused as ctx later)
  bf16* WtQKV = (bf16*)(ws + 0x1000000);           // 6 MiB
  bf16* Wot   = (bf16*)(ws + 0x1600000);           // 2 MiB
  bf16* Qb    = (bf16*)(ws + 0x1800000);           // 16 MiB
  bf16* Kb    = (bf16*)(ws + 0x2800000);           // 16 MiB
  bf16* Vtb   = (bf16*)(ws + 0x3800000);           // 16 MiB  (end: 72 MiB)
  bf16* ctx   = xb;                                // alias: xb dead after QKV GEMM

  cvt_x_kernel<<<dim3(Mn * Dn / 8 / 256), dim3(256), 0, stream>>>(x, xb, Mn * Dn / 8);
  transpose_w_kernel<<<dim3(16, 16, 4), dim3(256), 0, stream>>>(Wq, Wk, Wv, Wo, WtQKV, Wot);
  gemm_kernel<0><<<dim3(24, 64), dim3(256), 0, stream>>>(xb, WtQKV, nullptr, nullptr, Qb, Kb, Vtb);
  attn_kernel<<<dim3(16, 64), dim3(256), 0, stream>>>(Qb, Kb, Vtb, ctx);
  gemm_kernel<1><<<dim3(8, 64), dim3(256), 0, stream>>>(ctx, Wot, (float*)d_out, bo,
                                                        nullptr, nullptr, nullptr);
}